// Round 13
// baseline (270.386 us; speedup 1.0000x reference)
//
#include <hip/hip_runtime.h>
#include <hip/hip_fp16.h>
#include <math.h>

#define NTH 5
#define GLO 66
#define GHI 132
#define PS (GLO + 4096 + GHI)   // plane stride in 16B granules = 4294

// theta = {2,1,0,-1,-2} deg; t = -theta*pi/180; alpha=cos t, beta=sin t
#define ALP0 0.99939082701909576f
#define ALP1 0.99984769515639127f
constexpr float ALPc[5] = {ALP0, ALP1, 1.0f, ALP1, ALP0};
constexpr float BETc[5] = {0.03489949670250097f, 0.01745240643728351f, 0.0f,
                           -0.01745240643728351f, -0.03489949670250097f};

__device__ __forceinline__ unsigned h2bits(float a, float b) {
    __half2 h = __floats2half2_rn(a, b);
    return *(unsigned*)&h;
}
__device__ __forceinline__ __half2 h2(unsigned u) { return *(__half2*)&u; }

__device__ __forceinline__ int pkadd(int a, int b) {
    __half2 r = __hadd2(*(__half2*)&a, *(__half2*)&b);
    return *(int*)&r;
}
// sum half2 over 16-lane groups, pure DPP (VALU pipe, no DS ops)
__device__ __forceinline__ int hred16(__half2 v) {
    int x = *(int*)&v;
    int t = __builtin_amdgcn_update_dpp(0, x, 0xB1, 0xF, 0xF, true);   // quad_perm [1,0,3,2]
    x = pkadd(x, t);
    t = __builtin_amdgcn_update_dpp(0, x, 0x4E, 0xF, 0xF, true);       // quad_perm [2,3,0,1]
    x = pkadd(x, t);
    t = __builtin_amdgcn_update_dpp(0, x, 0x141, 0xF, 0xF, true);      // row_half_mirror
    x = pkadd(x, t);
    t = __builtin_amdgcn_update_dpp(0, x, 0x140, 0xF, 0xF, true);      // row_mirror
    x = pkadd(x, t);
    return x;
}

// ---- pack fm1/fm2 (f32) -> fp16 plane-split layouts in workspace ------------
// fm1h and fm2h: [g=128][plane=2][px=4096][8 batches] (16B granule)
// 256 blocks: bid = g*2 + half; each handles 2048 px of group g
__global__ void pack_kernel(const float* __restrict__ fm1,
                            const float* __restrict__ fm2,
                            __half* __restrict__ fm1h,
                            __half* __restrict__ fm2h) {
    const int g = blockIdx.x >> 1;
    const int half = blockIdx.x & 1;
    const int tid = threadIdx.x;
    const size_t inb = (size_t)g * 16 * 4096;
    #pragma unroll
    for (int i = 0; i < 2; i++) {
        const int p = half * 2048 + tid + 1024 * i;
        uint4 wa, wb, va, vb;
        wa.x = h2bits(fm1[inb + 0 * 4096 + p], fm1[inb + 1 * 4096 + p]);
        wa.y = h2bits(fm1[inb + 2 * 4096 + p], fm1[inb + 3 * 4096 + p]);
        wa.z = h2bits(fm1[inb + 4 * 4096 + p], fm1[inb + 5 * 4096 + p]);
        wa.w = h2bits(fm1[inb + 6 * 4096 + p], fm1[inb + 7 * 4096 + p]);
        wb.x = h2bits(fm1[inb + 8 * 4096 + p], fm1[inb + 9 * 4096 + p]);
        wb.y = h2bits(fm1[inb + 10 * 4096 + p], fm1[inb + 11 * 4096 + p]);
        wb.z = h2bits(fm1[inb + 12 * 4096 + p], fm1[inb + 13 * 4096 + p]);
        wb.w = h2bits(fm1[inb + 14 * 4096 + p], fm1[inb + 15 * 4096 + p]);
        va.x = h2bits(fm2[inb + 0 * 4096 + p], fm2[inb + 1 * 4096 + p]);
        va.y = h2bits(fm2[inb + 2 * 4096 + p], fm2[inb + 3 * 4096 + p]);
        va.z = h2bits(fm2[inb + 4 * 4096 + p], fm2[inb + 5 * 4096 + p]);
        va.w = h2bits(fm2[inb + 6 * 4096 + p], fm2[inb + 7 * 4096 + p]);
        vb.x = h2bits(fm2[inb + 8 * 4096 + p], fm2[inb + 9 * 4096 + p]);
        vb.y = h2bits(fm2[inb + 10 * 4096 + p], fm2[inb + 11 * 4096 + p]);
        vb.z = h2bits(fm2[inb + 12 * 4096 + p], fm2[inb + 13 * 4096 + p]);
        vb.w = h2bits(fm2[inb + 14 * 4096 + p], fm2[inb + 15 * 4096 + p]);
        *(uint4*)(fm1h + ((size_t)(g * 2 + 0) * 4096 + p) * 8) = wa;
        *(uint4*)(fm1h + ((size_t)(g * 2 + 1) * 4096 + p) * 8) = wb;
        *(uint4*)(fm2h + ((size_t)(g * 2 + 0) * 4096 + p) * 8) = va;
        *(uint4*)(fm2h + ((size_t)(g * 2 + 1) * 4096 + p) * 8) = vb;
    }
}

// ---- coord/weight tables + denominators -------------------------------------
// tabW entry (uint4): pre-broadcast weights {w00|w00, w01|w01, w10|w10, w11|w11}
// tabM entry (uint2): {mk|mk, b0}; zero weights when x>=ow or y>=oh
// denom[s*5+ti]: sum_px mk (f32). Identity (ti=2) written by tj==0 as ow*oh.
// 400 blocks = (s*4+tj)*4 + quarter; 256 threads; 4 px-iters each
__global__ void table_kernel(uint4* __restrict__ tabW, uint2* __restrict__ tabM,
                             float* __restrict__ denom) {
    const int bid = blockIdx.x >> 2;      // 100 = s*4 + tj
    const int quarter = blockIdx.x & 3;
    const int s = bid >> 2, tj = bid & 3;
    const int ti = tj < 2 ? tj : tj + 1;  // skip identity theta index 2
    const int tid = threadIdx.x;          // 256
    const int bh = (s / 5) - 2;
    const int bv = (s % 5) - 2;
    const int ox2 = bh >= 0 ? bh : 0;
    const int ow = 64 - (bh >= 0 ? bh : -bh);
    const int oy2 = bv >= 0 ? bv : 0;
    const int oh = 64 - (bv >= 0 ? bv : -bv);
    const float cx = 0.5f * (float)ow;
    const float cy = 0.5f * (float)oh;
    const float alpha = ALPc[ti], beta = BETc[ti];
    float macc = 0.0f;
    for (int i = 0; i < 4; i++) {
        const int px = quarter * 1024 + tid + 256 * i;   // y*64 + x
        const int y = px >> 6, x = px & 63;
        uint4 w = make_uint4(0u, 0u, 0u, 0u);
        uint2 m = make_uint2(0u, (unsigned)GLO);
        if (x < ow && y < oh) {
            const float xs = (float)x, yf = (float)y;
            const float hx = fmaf(alpha, xs, (1.0f - alpha) * cx - beta * cy);
            const float hy = fmaf(-beta, xs, beta * cx + (1.0f - alpha) * cy);
            const float xsrc = fmaf(beta, yf, hx);
            const float ysrc = fmaf(alpha, yf, hy);
            const float x0f = floorf(xsrc), y0f = floorf(ysrc);
            const float wx = xsrc - x0f, wy = ysrc - y0f;
            const int x0 = (int)x0f, y0 = (int)y0f;
            const float ax0 = ((unsigned)x0 < (unsigned)ow) ? (1.f - wx) : 0.f;
            const float ax1 = ((unsigned)(x0 + 1) < (unsigned)ow) ? wx : 0.f;
            const float ay0 = ((unsigned)y0 < (unsigned)oh) ? (1.f - wy) : 0.f;
            const float ay1 = ((unsigned)(y0 + 1) < (unsigned)oh) ? wy : 0.f;
            const int x0c = min(max(x0, -1), ow - 1);
            const int y0c = min(max(y0, -1), oh - 1);
            const float mk = (ax0 + ax1) * (ay0 + ay1);
            w.x = h2bits(ay0 * ax0, ay0 * ax0);
            w.y = h2bits(ay0 * ax1, ay0 * ax1);
            w.z = h2bits(ay1 * ax0, ay1 * ax0);
            w.w = h2bits(ay1 * ax1, ay1 * ax1);
            m.x = h2bits(mk, mk);
            m.y = (unsigned)(GLO + (y0c + oy2) * 64 + (x0c + ox2));
            macc += mk;
        }
        tabW[(size_t)bid * 4096 + px] = w;
        tabM[(size_t)bid * 4096 + px] = m;
    }
    // block-partial reduce of macc -> atomicAdd (denom zeroed host-side)
    #pragma unroll
    for (int off = 32; off; off >>= 1) macc += __shfl_xor(macc, off);
    __shared__ float mred[4];
    if ((tid & 63) == 0) mred[tid >> 6] = macc;
    __syncthreads();
    if (tid == 0) {
        atomicAdd(&denom[s * 5 + ti], mred[0] + mred[1] + mred[2] + mred[3]);
        if (tj == 0 && quarter == 0)
            denom[s * 5 + 2] = (float)(ow * oh);  // identity: mk=1 in-window
    }
}

// ---- main: 512 blocks = hf(2) x pl(2) x g(128); balanced hf per CU ----------
__launch_bounds__(1024, 8)
__global__ void wrsl_main(const __half* __restrict__ fm1h,
                          const __half* __restrict__ fm2h,
                          const uint4* __restrict__ tabW,
                          const uint2* __restrict__ tabM,
                          const float* __restrict__ denom,
                          float* __restrict__ out) {
    __shared__ uint4 lds[PS];            // 68,704 B: one 8-batch plane + guards
    __shared__ float redm[16][4][40];    // 10,240 B
    __shared__ float colsum[40];

    const int tid = threadIdx.x;
    const int g = blockIdx.x & 127;
    const int pl = (blockIdx.x >> 7) & 1;
    const int hf = (blockIdx.x >> 8) & 1;   // high bit: each CU gets one of each
    const int sBeg = hf ? 13 : 0;
    const int sEnd = hf ? 25 : 13;
    const size_t pbase = (size_t)(g * 2 + pl) * 4096;

    // stage this plane of fm2h, zero guards
    {
        const uint4* src = (const uint4*)(fm2h + pbase * 8);
        #pragma unroll
        for (int i = 0; i < 4; i++)
            lds[GLO + tid + 1024 * i] = src[tid + 1024 * i];
        if (tid < GLO + GHI) {
            const int off = (tid < GLO) ? tid : (4096 + tid);
            lds[off] = make_uint4(0u, 0u, 0u, 0u);
        }
    }
    const int lane = tid & 63, wid = tid >> 6;
    __syncthreads();

    float best = 3.4028234663852886e38f;  // meaningful on tid<8

    for (int s = sBeg; s < sEnd; s++) {
        const int bh = (s / 5) - 2;
        const int bv = (s % 5) - 2;
        const int ox1 = bh >= 0 ? 0 : -bh;
        const int ox2 = bh >= 0 ? bh : 0;
        const int ow = 64 - (bh >= 0 ? bh : -bh);
        const int oy1 = bv >= 0 ? 0 : -bv;
        const int oy2 = bv >= 0 ? bv : 0;
        const int oh = 64 - (bv >= 0 ? bv : -bv);
        const int xcap = ox1 + min(lane, ow - 1);

        // negated r1 (8 batches) for this wave's 4 rows; reused over 5 thetas
        uint4 nr[4];
        #pragma unroll
        for (int k = 0; k < 4; k++) {
            const int p1 = (oy1 + min(wid + 16 * k, oh - 1)) * 64 + xcap;
            uint4 a = *(const uint4*)(fm1h + (pbase + p1) * 8);
            a.x ^= 0x80008000u; a.y ^= 0x80008000u; a.z ^= 0x80008000u; a.w ^= 0x80008000u;
            nr[k] = a;
        }

        // issue theta-0 table loads NOW; identity compute below hides latency
        const uint4* twbase = tabW + (size_t)(s * 4) * 4096;
        const uint2* tmbase = tabM + (size_t)(s * 4) * 4096;
        uint4 tw[4];
        uint2 tm[4];
        #pragma unroll
        for (int k = 0; k < 4; k++) {
            const int e = (wid + 16 * k) * 64 + lane;
            tw[k] = twbase[e];
            tm[k] = tmbase[e];
        }

        // ---- identity theta: taps straight from global (L2), DS pipe freed --
        {
            const float xinf = (lane < ow) ? 1.0f : 0.0f;
            const __half2 z2 = __float2half2_rn(0.0f);
            __half2 se[4] = {z2, z2, z2, z2};
            #pragma unroll
            for (int k = 0; k < 4; k++) {
                const int y = wid + 16 * k;
                const __half2 msk = __float2half2_rn((y < oh) ? xinf : 0.0f);
                const int idxp = (oy2 + min(y, oh - 1)) * 64 + ox2 + lane;  // row-clamped: in-bounds, finite
                const uint4 qa = *(const uint4*)(fm2h + (pbase + idxp) * 8);
                #define LIGHT(SE, C)                                          \
                {                                                             \
                    __half2 d = __hmul2(__hadd2(h2(qa.C), h2(nr[k].C)), msk); \
                    SE = __hfma2(d, d, SE);                                   \
                }
                LIGHT(se[0], x) LIGHT(se[1], y) LIGHT(se[2], z) LIGHT(se[3], w)
                #undef LIGHT
            }
            int r0 = hred16(se[0]), r1 = hred16(se[1]);
            int r2 = hred16(se[2]), r3 = hred16(se[3]);
            if ((lane & 15) == 0) {
                float2 f0 = __half22float2(h2(r0)), f1 = __half22float2(h2(r1));
                float2 f2 = __half22float2(h2(r2)), f3 = __half22float2(h2(r3));
                float4* dst = (float4*)&redm[wid][lane >> 4][2 * 8];
                dst[0] = make_float4(f0.x, f0.y, f1.x, f1.y);
                dst[1] = make_float4(f2.x, f2.y, f3.x, f3.y);
            }
        }

        // ---- 4 non-identity thetas, software-pipelined table loads ----------
        #pragma unroll
        for (int tj = 0; tj < 4; tj++) {
            const int ti = tj < 2 ? tj : tj + 1;
            // prefetch next theta's table slice while computing this one
            uint4 twn[4];
            uint2 tmn[4];
            if (tj < 3) {
                const uint4* twq = twbase + (size_t)(tj + 1) * 4096;
                const uint2* tmq = tmbase + (size_t)(tj + 1) * 4096;
                #pragma unroll
                for (int k = 0; k < 4; k++) {
                    const int e = (wid + 16 * k) * 64 + lane;
                    twn[k] = twq[e];
                    tmn[k] = tmq[e];
                }
            }

            const __half2 z2 = __float2half2_rn(0.0f);
            __half2 se[4] = {z2, z2, z2, z2};
            #pragma unroll
            for (int k = 0; k < 4; k++) {
                const __half2 w00p = h2(tw[k].x), w01p = h2(tw[k].y);
                const __half2 w10p = h2(tw[k].z), w11p = h2(tw[k].w);
                const __half2 mkp = h2(tm[k].x);
                const int b0 = (int)tm[k].y;
                const uint4 q00 = lds[b0], q01 = lds[b0 + 1];
                const uint4 q10 = lds[b0 + 64], q11 = lds[b0 + 65];
                #define FULL(SE, C)                                        \
                {                                                          \
                    __half2 r = __hfma2(w00p, h2(q00.C), h2(nr[k].C));     \
                    r = __hfma2(w01p, h2(q01.C), r);                       \
                    r = __hfma2(w10p, h2(q10.C), r);                       \
                    r = __hfma2(w11p, h2(q11.C), r);                       \
                    SE = __hfma2(__hmul2(r, mkp), r, SE);                  \
                }
                FULL(se[0], x) FULL(se[1], y) FULL(se[2], z) FULL(se[3], w)
                #undef FULL
            }
            int r0 = hred16(se[0]), r1 = hred16(se[1]);
            int r2 = hred16(se[2]), r3 = hred16(se[3]);
            if ((lane & 15) == 0) {
                float2 f0 = __half22float2(h2(r0)), f1 = __half22float2(h2(r1));
                float2 f2 = __half22float2(h2(r2)), f3 = __half22float2(h2(r3));
                float4* dst = (float4*)&redm[wid][lane >> 4][ti * 8];
                dst[0] = make_float4(f0.x, f0.y, f1.x, f1.y);
                dst[1] = make_float4(f2.x, f2.y, f3.x, f3.y);
            }
            if (tj < 3) {
                #pragma unroll
                for (int k = 0; k < 4; k++) {
                    tw[k] = twn[k];
                    tm[k] = tmn[k];
                }
            }
        }

        __syncthreads();  // B1: redm complete
        if (tid < 40) {
            float sum = 0.0f;
            #pragma unroll 8
            for (int w = 0; w < 16; w++) {
                sum += redm[w][0][tid] + redm[w][1][tid] + redm[w][2][tid] + redm[w][3][tid];
            }
            colsum[tid] = sum;
        }
        __syncthreads();  // B2: colsum ready, redm reusable
        if (tid < 8) {
            #pragma unroll
            for (int t2 = 0; t2 < NTH; t2++)
                best = fminf(best, colsum[t2 * 8 + tid] / denom[s * 5 + t2]);
        }
    }
    if (tid < 8)
        atomicMin((unsigned int*)&out[g * 16 + pl * 8 + tid], __float_as_uint(best));
}

extern "C" void kernel_launch(void* const* d_in, const int* in_sizes, int n_in,
                              void* d_out, int out_size, void* d_ws, size_t ws_size,
                              hipStream_t stream) {
    const float* fm1 = (const float*)d_in[0];
    const float* fm2 = (const float*)d_in[1];
    float* out = (float*)d_out;
    // ws: fm1h 16MB | fm2h 16MB | tabW 6.55MB | tabM 3.28MB | denom (~42MB total)
    const size_t TABW_OFF = (size_t)32 << 20;
    const size_t TABM_OFF = TABW_OFF + (size_t)100 * 4096 * 16;
    const size_t DEN_OFF = TABM_OFF + (size_t)100 * 4096 * 8;
    __half* fm1h = (__half*)d_ws;
    __half* fm2h = (__half*)((char*)d_ws + ((size_t)16 << 20));
    uint4* tabW = (uint4*)((char*)d_ws + TABW_OFF);
    uint2* tabM = (uint2*)((char*)d_ws + TABM_OFF);
    float* denom = (float*)((char*)d_ws + DEN_OFF);

    hipMemsetAsync(d_out, 0x7F, (size_t)out_size * 4, stream);  // +huge for atomicMin
    hipMemsetAsync(denom, 0, 125 * 4, stream);                  // for atomicAdd partials
    pack_kernel<<<256, 1024, 0, stream>>>(fm1, fm2, fm1h, fm2h);
    table_kernel<<<400, 256, 0, stream>>>(tabW, tabM, denom);
    wrsl_main<<<512, 1024, 0, stream>>>(fm1h, fm2h, tabW, tabM, denom, out);
}

// Round 14
// 184.662 us; speedup vs baseline: 1.4642x; 1.4642x over previous
//
#include <hip/hip_runtime.h>
#include <hip/hip_fp16.h>
#include <math.h>

#define NTH 5
#define GLO 66
#define GHI 132
#define PS (GLO + 4096 + GHI)   // plane stride in 16B granules = 4294

// theta = {2,1,0,-1,-2} deg; t = -theta*pi/180; alpha=cos t, beta=sin t
#define ALP0 0.99939082701909576f
#define ALP1 0.99984769515639127f
constexpr float ALPc[5] = {ALP0, ALP1, 1.0f, ALP1, ALP0};
constexpr float BETc[5] = {0.03489949670250097f, 0.01745240643728351f, 0.0f,
                           -0.01745240643728351f, -0.03489949670250097f};

__device__ __forceinline__ unsigned h2bits(float a, float b) {
    __half2 h = __floats2half2_rn(a, b);
    return *(unsigned*)&h;
}
__device__ __forceinline__ __half2 h2(unsigned u) { return *(__half2*)&u; }

__device__ __forceinline__ int pkadd(int a, int b) {
    __half2 r = __hadd2(*(__half2*)&a, *(__half2*)&b);
    return *(int*)&r;
}
// sum half2 over 16-lane groups, pure DPP (VALU pipe, no DS ops)
__device__ __forceinline__ int hred16(__half2 v) {
    int x = *(int*)&v;
    int t = __builtin_amdgcn_update_dpp(0, x, 0xB1, 0xF, 0xF, true);   // quad_perm [1,0,3,2]
    x = pkadd(x, t);
    t = __builtin_amdgcn_update_dpp(0, x, 0x4E, 0xF, 0xF, true);       // quad_perm [2,3,0,1]
    x = pkadd(x, t);
    t = __builtin_amdgcn_update_dpp(0, x, 0x141, 0xF, 0xF, true);      // row_half_mirror
    x = pkadd(x, t);
    t = __builtin_amdgcn_update_dpp(0, x, 0x140, 0xF, 0xF, true);      // row_mirror
    x = pkadd(x, t);
    return x;
}

// ---- pack fm1/fm2 (f32) -> fp16 plane-split layouts in workspace ------------
// fm1h and fm2h: [g=128][plane=2][px=4096][8 batches] (16B granule)
// 256 blocks: bid = g*2 + half; each handles 2048 px of group g
__global__ void pack_kernel(const float* __restrict__ fm1,
                            const float* __restrict__ fm2,
                            __half* __restrict__ fm1h,
                            __half* __restrict__ fm2h) {
    const int g = blockIdx.x >> 1;
    const int half = blockIdx.x & 1;
    const int tid = threadIdx.x;
    const size_t inb = (size_t)g * 16 * 4096;
    #pragma unroll
    for (int i = 0; i < 2; i++) {
        const int p = half * 2048 + tid + 1024 * i;
        uint4 wa, wb, va, vb;
        wa.x = h2bits(fm1[inb + 0 * 4096 + p], fm1[inb + 1 * 4096 + p]);
        wa.y = h2bits(fm1[inb + 2 * 4096 + p], fm1[inb + 3 * 4096 + p]);
        wa.z = h2bits(fm1[inb + 4 * 4096 + p], fm1[inb + 5 * 4096 + p]);
        wa.w = h2bits(fm1[inb + 6 * 4096 + p], fm1[inb + 7 * 4096 + p]);
        wb.x = h2bits(fm1[inb + 8 * 4096 + p], fm1[inb + 9 * 4096 + p]);
        wb.y = h2bits(fm1[inb + 10 * 4096 + p], fm1[inb + 11 * 4096 + p]);
        wb.z = h2bits(fm1[inb + 12 * 4096 + p], fm1[inb + 13 * 4096 + p]);
        wb.w = h2bits(fm1[inb + 14 * 4096 + p], fm1[inb + 15 * 4096 + p]);
        va.x = h2bits(fm2[inb + 0 * 4096 + p], fm2[inb + 1 * 4096 + p]);
        va.y = h2bits(fm2[inb + 2 * 4096 + p], fm2[inb + 3 * 4096 + p]);
        va.z = h2bits(fm2[inb + 4 * 4096 + p], fm2[inb + 5 * 4096 + p]);
        va.w = h2bits(fm2[inb + 6 * 4096 + p], fm2[inb + 7 * 4096 + p]);
        vb.x = h2bits(fm2[inb + 8 * 4096 + p], fm2[inb + 9 * 4096 + p]);
        vb.y = h2bits(fm2[inb + 10 * 4096 + p], fm2[inb + 11 * 4096 + p]);
        vb.z = h2bits(fm2[inb + 12 * 4096 + p], fm2[inb + 13 * 4096 + p]);
        vb.w = h2bits(fm2[inb + 14 * 4096 + p], fm2[inb + 15 * 4096 + p]);
        *(uint4*)(fm1h + ((size_t)(g * 2 + 0) * 4096 + p) * 8) = wa;
        *(uint4*)(fm1h + ((size_t)(g * 2 + 1) * 4096 + p) * 8) = wb;
        *(uint4*)(fm2h + ((size_t)(g * 2 + 0) * 4096 + p) * 8) = va;
        *(uint4*)(fm2h + ((size_t)(g * 2 + 1) * 4096 + p) * 8) = vb;
    }
}

// ---- coord/weight table + denominators --------------------------------------
// tab entry: {w00|w01, w10|w11, mk|0, b0}; zero weights when x>=ow or y>=oh
// denom[s*5+ti]: sum_px mk. Identity (ti=2) written by the tj==0 block as ow*oh.
__global__ void table_kernel(uint4* __restrict__ tab, float* __restrict__ denom) {
    const int bid = blockIdx.x;      // 100 = s*4 + tj
    const int s = bid >> 2, tj = bid & 3;
    const int ti = tj < 2 ? tj : tj + 1;  // skip identity theta index 2
    const int tid = threadIdx.x;     // 256
    const int bh = (s / 5) - 2;
    const int bv = (s % 5) - 2;
    const int ox2 = bh >= 0 ? bh : 0;
    const int ow = 64 - (bh >= 0 ? bh : -bh);
    const int oy2 = bv >= 0 ? bv : 0;
    const int oh = 64 - (bv >= 0 ? bv : -bv);
    const float cx = 0.5f * (float)ow;
    const float cy = 0.5f * (float)oh;
    const float alpha = ALPc[ti], beta = BETc[ti];
    __shared__ float mred[4];
    float macc = 0.0f;
    for (int i = 0; i < 16; i++) {
        const int px = tid + 256 * i;   // y*64 + x
        const int y = px >> 6, x = px & 63;
        uint4 e = make_uint4(0u, 0u, 0u, (unsigned)GLO);
        if (x < ow && y < oh) {
            const float xs = (float)x, yf = (float)y;
            const float hx = fmaf(alpha, xs, (1.0f - alpha) * cx - beta * cy);
            const float hy = fmaf(-beta, xs, beta * cx + (1.0f - alpha) * cy);
            const float xsrc = fmaf(beta, yf, hx);
            const float ysrc = fmaf(alpha, yf, hy);
            const float x0f = floorf(xsrc), y0f = floorf(ysrc);
            const float wx = xsrc - x0f, wy = ysrc - y0f;
            const int x0 = (int)x0f, y0 = (int)y0f;
            const float ax0 = ((unsigned)x0 < (unsigned)ow) ? (1.f - wx) : 0.f;
            const float ax1 = ((unsigned)(x0 + 1) < (unsigned)ow) ? wx : 0.f;
            const float ay0 = ((unsigned)y0 < (unsigned)oh) ? (1.f - wy) : 0.f;
            const float ay1 = ((unsigned)(y0 + 1) < (unsigned)oh) ? wy : 0.f;
            const int x0c = min(max(x0, -1), ow - 1);
            const int y0c = min(max(y0, -1), oh - 1);
            const float mk = (ax0 + ax1) * (ay0 + ay1);
            e.x = h2bits(ay0 * ax0, ay0 * ax1);
            e.y = h2bits(ay1 * ax0, ay1 * ax1);
            e.z = h2bits(mk, 0.0f);
            e.w = (unsigned)(GLO + (y0c + oy2) * 64 + (x0c + ox2));
            macc += mk;
        }
        tab[(size_t)bid * 4096 + px] = e;
    }
    // block-reduce macc (f32 from the f32 mk, matching ref summation magnitude)
    #pragma unroll
    for (int off = 32; off; off >>= 1) macc += __shfl_xor(macc, off);
    if ((tid & 63) == 0) mred[tid >> 6] = macc;
    __syncthreads();
    if (tid == 0) {
        denom[s * 5 + ti] = mred[0] + mred[1] + mred[2] + mred[3];
        if (tj == 0) denom[s * 5 + 2] = (float)(ow * oh);  // identity: mk=1 in-window
    }
}

// ---- main: 512 blocks = hf(2) x pl(2) x g(128); hf on high bit balances CUs -
__launch_bounds__(1024, 8)
__global__ void wrsl_main(const __half* __restrict__ fm1h,
                          const __half* __restrict__ fm2h,
                          const uint4* __restrict__ tab,
                          const float* __restrict__ denom,
                          float* __restrict__ out) {
    __shared__ uint4 lds[PS];            // 68,704 B: one 8-batch plane + guards
    __shared__ float redm[16][4][40];    // 10,240 B
    __shared__ float colsum[40];

    const int tid = threadIdx.x;
    const int g = blockIdx.x & 127;
    const int pl = (blockIdx.x >> 7) & 1;
    const int hf = (blockIdx.x >> 8) & 1;   // high bit: each CU gets one of each
    const int sBeg = hf ? 13 : 0;
    const int sEnd = hf ? 25 : 13;
    const size_t pbase = (size_t)(g * 2 + pl) * 4096;

    // stage this plane of fm2h, zero guards
    {
        const uint4* src = (const uint4*)(fm2h + pbase * 8);
        #pragma unroll
        for (int i = 0; i < 4; i++)
            lds[GLO + tid + 1024 * i] = src[tid + 1024 * i];
        if (tid < GLO + GHI) {
            const int off = (tid < GLO) ? tid : (4096 + tid);
            lds[off] = make_uint4(0u, 0u, 0u, 0u);
        }
    }
    const int lane = tid & 63, wid = tid >> 6;
    __syncthreads();

    float best = 3.4028234663852886e38f;  // meaningful on tid<8

    for (int s = sBeg; s < sEnd; s++) {
        const int bh = (s / 5) - 2;
        const int bv = (s % 5) - 2;
        const int ox1 = bh >= 0 ? 0 : -bh;
        const int ox2 = bh >= 0 ? bh : 0;
        const int ow = 64 - (bh >= 0 ? bh : -bh);
        const int oy1 = bv >= 0 ? 0 : -bv;
        const int oy2 = bv >= 0 ? bv : 0;
        const int oh = 64 - (bv >= 0 ? bv : -bv);
        const int xcap = ox1 + min(lane, ow - 1);

        // negated r1 (8 batches) for this wave's 4 rows; reused over 5 thetas
        uint4 nr[4];
        #pragma unroll
        for (int k = 0; k < 4; k++) {
            const int p1 = (oy1 + min(wid + 16 * k, oh - 1)) * 64 + xcap;
            uint4 a = *(const uint4*)(fm1h + (pbase + p1) * 8);
            a.x ^= 0x80008000u; a.y ^= 0x80008000u; a.z ^= 0x80008000u; a.w ^= 0x80008000u;
            nr[k] = a;
        }

        // issue theta-0 table loads NOW; identity compute below hides their latency
        const uint4* tqbase = tab + (size_t)(s * 4) * 4096;
        uint4 tv[4];
        #pragma unroll
        for (int k = 0; k < 4; k++)
            tv[k] = tqbase[(wid + 16 * k) * 64 + lane];

        // ---- identity theta (no table), branchless via row/col validity mask
        {
            const float xinf = (lane < ow) ? 1.0f : 0.0f;
            const __half2 z2 = __float2half2_rn(0.0f);
            __half2 se[4] = {z2, z2, z2, z2};
            #pragma unroll
            for (int k = 0; k < 4; k++) {
                const int y = wid + 16 * k;
                const __half2 msk = __float2half2_rn((y < oh) ? xinf : 0.0f);
                const int idx = GLO + (oy2 + y) * 64 + ox2 + lane;
                const uint4 qa = lds[idx];
                #define LIGHT(SE, C)                                          \
                {                                                             \
                    __half2 d = __hmul2(__hadd2(h2(qa.C), h2(nr[k].C)), msk); \
                    SE = __hfma2(d, d, SE);                                   \
                }
                LIGHT(se[0], x) LIGHT(se[1], y) LIGHT(se[2], z) LIGHT(se[3], w)
                #undef LIGHT
            }
            int r0 = hred16(se[0]), r1 = hred16(se[1]);
            int r2 = hred16(se[2]), r3 = hred16(se[3]);
            if ((lane & 15) == 0) {
                float2 f0 = __half22float2(h2(r0)), f1 = __half22float2(h2(r1));
                float2 f2 = __half22float2(h2(r2)), f3 = __half22float2(h2(r3));
                float4* dst = (float4*)&redm[wid][lane >> 4][2 * 8];
                dst[0] = make_float4(f0.x, f0.y, f1.x, f1.y);
                dst[1] = make_float4(f2.x, f2.y, f3.x, f3.y);
            }
        }

        // ---- 4 non-identity thetas, software-pipelined table loads ----------
        #pragma unroll
        for (int tj = 0; tj < 4; tj++) {
            const int ti = tj < 2 ? tj : tj + 1;
            // prefetch next theta's table slice while computing this one
            uint4 tvn[4];
            if (tj < 3) {
                const uint4* tqn = tqbase + (size_t)(tj + 1) * 4096;
                #pragma unroll
                for (int k = 0; k < 4; k++)
                    tvn[k] = tqn[(wid + 16 * k) * 64 + lane];
            }

            const __half2 z2 = __float2half2_rn(0.0f);
            __half2 se[4] = {z2, z2, z2, z2};
            #pragma unroll
            for (int k = 0; k < 4; k++) {
                const __half2 tx = h2(tv[k].x), ty = h2(tv[k].y);
                const __half2 w00p = __low2half2(tx), w01p = __high2half2(tx);
                const __half2 w10p = __low2half2(ty), w11p = __high2half2(ty);
                const __half2 mkp = __low2half2(h2(tv[k].z));
                const int b0 = (int)tv[k].w;
                const uint4 q00 = lds[b0], q01 = lds[b0 + 1];
                const uint4 q10 = lds[b0 + 64], q11 = lds[b0 + 65];
                #define FULL(SE, C)                                        \
                {                                                          \
                    __half2 r = __hfma2(w00p, h2(q00.C), h2(nr[k].C));     \
                    r = __hfma2(w01p, h2(q01.C), r);                       \
                    r = __hfma2(w10p, h2(q10.C), r);                       \
                    r = __hfma2(w11p, h2(q11.C), r);                       \
                    SE = __hfma2(__hmul2(r, mkp), r, SE);                  \
                }
                FULL(se[0], x) FULL(se[1], y) FULL(se[2], z) FULL(se[3], w)
                #undef FULL
            }
            int r0 = hred16(se[0]), r1 = hred16(se[1]);
            int r2 = hred16(se[2]), r3 = hred16(se[3]);
            if ((lane & 15) == 0) {
                float2 f0 = __half22float2(h2(r0)), f1 = __half22float2(h2(r1));
                float2 f2 = __half22float2(h2(r2)), f3 = __half22float2(h2(r3));
                float4* dst = (float4*)&redm[wid][lane >> 4][ti * 8];
                dst[0] = make_float4(f0.x, f0.y, f1.x, f1.y);
                dst[1] = make_float4(f2.x, f2.y, f3.x, f3.y);
            }
            if (tj < 3) {
                #pragma unroll
                for (int k = 0; k < 4; k++) tv[k] = tvn[k];
            }
        }

        __syncthreads();  // B1: redm complete
        if (tid < 40) {
            float sum = 0.0f;
            #pragma unroll 8
            for (int w = 0; w < 16; w++) {
                sum += redm[w][0][tid] + redm[w][1][tid] + redm[w][2][tid] + redm[w][3][tid];
            }
            colsum[tid] = sum;
        }
        __syncthreads();  // B2: colsum ready, redm reusable
        if (tid < 8) {
            #pragma unroll
            for (int t2 = 0; t2 < NTH; t2++)
                best = fminf(best, colsum[t2 * 8 + tid] / denom[s * 5 + t2]);
        }
    }
    if (tid < 8)
        atomicMin((unsigned int*)&out[g * 16 + pl * 8 + tid], __float_as_uint(best));
}

extern "C" void kernel_launch(void* const* d_in, const int* in_sizes, int n_in,
                              void* d_out, int out_size, void* d_ws, size_t ws_size,
                              hipStream_t stream) {
    const float* fm1 = (const float*)d_in[0];
    const float* fm2 = (const float*)d_in[1];
    float* out = (float*)d_out;
    // ws: fm1h 16MB | fm2h 16MB | tab 6.5MB | denom (needs ~38.8MB total)
    __half* fm1h = (__half*)d_ws;
    __half* fm2h = (__half*)((char*)d_ws + ((size_t)16 << 20));
    uint4* tab = (uint4*)((char*)d_ws + ((size_t)32 << 20));
    float* denom = (float*)((char*)d_ws + ((size_t)32 << 20) + (size_t)100 * 4096 * 16);

    hipMemsetAsync(d_out, 0x7F, (size_t)out_size * 4, stream);  // +huge for atomicMin
    pack_kernel<<<256, 1024, 0, stream>>>(fm1, fm2, fm1h, fm2h);
    table_kernel<<<100, 256, 0, stream>>>(tab, denom);
    wrsl_main<<<512, 1024, 0, stream>>>(fm1h, fm2h, tab, denom, out);
}